// Round 10
// baseline (69.908 us; speedup 1.0000x reference)
//
#include <hip/hip_runtime.h>
#include <cstdint>

#define B_ROWS 4096
#define N_ROWS 8192
#define D_DIM  256
#define BT     128                 // tile 128x128
#define TGRID  64                  // 8192 / 128
#define NJ     4                   // j-tiles per block
#define NBLOCKS 544                // sum_i ceil((64-i)/4), % 8 == 0
#define NKT    8                   // 256 / 32 K-steps per tile

typedef __attribute__((ext_vector_type(4))) float f32x4;
typedef __attribute__((ext_vector_type(8))) short bf16x8;
typedef __attribute__((ext_vector_type(4))) unsigned short u16x4;

__device__ __forceinline__ unsigned short f2bf(float f) {
    union { float f; unsigned u; } v; v.f = f;
    unsigned r = v.u + 0x7FFF + ((v.u >> 16) & 1);   // RNE
    return (unsigned short)(r >> 16);
}
__device__ __forceinline__ float bf2f(unsigned short h) {
    union { unsigned u; float f; } v; v.u = ((unsigned)h) << 16;
    return v.f;
}

__device__ __forceinline__ void gload16(const void* g, void* l) {
    __builtin_amdgcn_global_load_lds(
        (const __attribute__((address_space(1))) void*)g,
        (__attribute__((address_space(3))) void*)l, 16, 0, 0);
}

__device__ __forceinline__ f32x4 exp4(f32x4 v) {
    f32x4 r;
    r.x = __expf(v.x); r.y = __expf(v.y); r.z = __expf(v.z); r.w = __expf(v.w);
    return r;
}

// ------------- Kernel A: normalize both pair rows + pos dot, one pass -------------
__global__ __launch_bounds__(256) void normpos_kernel(const float* __restrict__ zi,
                                                      const float* __restrict__ zj,
                                                      unsigned short* __restrict__ zn,
                                                      float* __restrict__ pospartial) {
    int wid = threadIdx.x >> 6;
    int lane = threadIdx.x & 63;
    int p = blockIdx.x * 4 + wid;          // 0..B_ROWS-1
    f32x4 ga = *(const f32x4*)(zi + (size_t)p * D_DIM + lane * 4);
    f32x4 gb = *(const f32x4*)(zj + (size_t)p * D_DIM + lane * 4);
    float sa = ga.x * ga.x + ga.y * ga.y + ga.z * ga.z + ga.w * ga.w;
    float sb = gb.x * gb.x + gb.y * gb.y + gb.z * gb.z + gb.w * gb.w;
    #pragma unroll
    for (int m = 1; m < 64; m <<= 1) { sa += __shfl_xor(sa, m, 64); sb += __shfl_xor(sb, m, 64); }
    float fa = 1.41421356237309515f / fmaxf(sqrtf(sa), 1e-8f);
    float fb = 1.41421356237309515f / fmaxf(sqrtf(sb), 1e-8f);
    u16x4 oa, ob;
    oa.x = f2bf(ga.x * fa); oa.y = f2bf(ga.y * fa); oa.z = f2bf(ga.z * fa); oa.w = f2bf(ga.w * fa);
    ob.x = f2bf(gb.x * fb); ob.y = f2bf(gb.y * fb); ob.z = f2bf(gb.z * fb); ob.w = f2bf(gb.w * fb);
    *(u16x4*)(zn + (size_t)p * D_DIM + lane * 4) = oa;
    *(u16x4*)(zn + (size_t)(p + B_ROWS) * D_DIM + lane * 4) = ob;
    float d = bf2f(oa.x) * bf2f(ob.x) + bf2f(oa.y) * bf2f(ob.y)
            + bf2f(oa.z) * bf2f(ob.z) + bf2f(oa.w) * bf2f(ob.w);
    #pragma unroll
    for (int m = 1; m < 64; m <<= 1) d += __shfl_xor(d, m, 64);
    if (lane == 0) pospartial[p] = d;
}

// ------------- Kernel C: A-in-registers, 4 j-tiles per block, 1-sync dbuf -------------
// 256 thr = 4 waves (2x2), wave-tile 64x64 (acc 4x4). A-panel (128x256) staged via LDS
// once (two 32KB halves), reg-loaded to af[4][8] (static idx). Per K-step: stage B
// chunk (8KB) into alternating buffer AFTER the barrier, read bfr (4 ds_read), 16 MFMA.
// Plain __syncthreads only; swizzle chunk ^= (row>>1)&3 (verified 0-conflict).
__global__ __launch_bounds__(256, 2) void simclr_gemm_kernel(const unsigned short* __restrict__ zn,
                                                             float* __restrict__ P) {
    __shared__ unsigned short Astage[4 * 4096];   // 32 KB (staging half an A-panel)
    __shared__ unsigned short Bs[2][4096];        // 2 x 8 KB
    __shared__ float rPpart[2][BT];
    __shared__ float cPpart[2][BT];

    const int tid = threadIdx.x;
    const int lane = tid & 63, wid = tid >> 6;
    const int wr = wid >> 1, wc = wid & 1;        // 2x2 wave grid

    // XCD-bijective chunked swizzle (544 = 8 x 68)
    int bid = (int)((blockIdx.x & 7) * (NBLOCKS / 8) + (blockIdx.x >> 3));
    // decode bid -> (ti, jc): per ti, ceil((64-ti)/4) j-chunks
    int ti = 0, cum = 0;
    for (;;) {
        int c = (TGRID - ti + 3) >> 2;
        if (bid < cum + c) break;
        cum += c; ++ti;
    }
    const int jc = bid - cum;
    const int j0 = ti + 4 * jc;
    const int nj = min(NJ, TGRID - j0);
    const int G = nj * NKT;

    const char* gA = (const char*)zn + (size_t)ti * BT * 512;   // row stride 512 B

    // staging geometry (8KB chunk = 128 rows x 64B): thread -> rows {tid>>2, 64+tid>>2},
    // 16B slot tid&3; source chunk pre-swizzled sch = (tid&3) ^ ((tid>>3)&3) = slot^((row>>1)&3)
    const int r0 = tid >> 2;
    const int sch = (tid & 3) ^ ((tid >> 3) & 3);
    const size_t gof0 = (size_t)r0 * 512 + (size_t)sch * 16;
    const size_t gof1 = (size_t)(64 + r0) * 512 + (size_t)sch * 16;
    const unsigned lo0 = (unsigned)tid * 8;          // ushort index (byte tid*16)
    const unsigned lo1 = 2048u + (unsigned)tid * 8;  // row 64 = ushort 2048

    // frag read: row r -> lds k-chunk kc = (lane>>4) ^ ((r>>1)&3); frag row bases x16
    const int kc = (lane >> 4) ^ (((lane & 15) >> 1) & 3);
    const int arow = wr * 64 + (lane & 15);
    const int brow = wc * 64 + (lane & 15);

    // ---- prologue: stage A panel in two 32KB halves, reg-load af[m][kt] (static) ----
    bf16x8 af[4][8];                                 // 128 VGPR
    #pragma unroll
    for (int h = 0; h < 2; ++h) {
        #pragma unroll
        for (int s = 0; s < 4; ++s) {
            size_t kb = (size_t)(h * 4 + s) * 64;
            gload16(gA + gof0 + kb, &Astage[s * 4096 + lo0]);
            gload16(gA + gof1 + kb, &Astage[s * 4096 + lo1]);
        }
        __syncthreads();                             // A chunks staged
        #pragma unroll
        for (int s = 0; s < 4; ++s)
            #pragma unroll
            for (int m = 0; m < 4; ++m)
                af[m][h * 4 + s] = *(const bf16x8*)&Astage[s * 4096 + (arow + m * 16) * 32 + kc * 8];
        __syncthreads();                             // reg-loads drained before restage
    }

#define STAGE_B(g_) do {                                                     \
    int jt_ = (g_) >> 3;                                                     \
    size_t kb_ = (size_t)((g_) & 7) * 64;                                    \
    const char* gBp = (const char*)zn + (size_t)(j0 + jt_) * BT * 512;       \
    gload16(gBp + gof0 + kb_, &Bs[(g_) & 1][lo0]);                           \
    gload16(gBp + gof1 + kb_, &Bs[(g_) & 1][lo1]);                           \
} while (0)

    STAGE_B(0);

    f32x4 acc[4][4];
    #pragma unroll
    for (int m = 0; m < 4; ++m)
        #pragma unroll
        for (int n = 0; n < 4; ++n)
            acc[m][n] = (f32x4){0.f, 0.f, 0.f, 0.f};

    for (int jt = 0; jt < nj; ++jt) {
        const int tj = j0 + jt;
        #pragma unroll
        for (int kt = 0; kt < NKT; ++kt) {           // kt static (af index)
            const int g = jt * NKT + kt;
            __syncthreads();                         // Bs[g&1] staged; prior reads of Bs[(g+1)&1] drained
            bf16x8 bfr[4];
            #pragma unroll
            for (int n = 0; n < 4; ++n)
                bfr[n] = *(const bf16x8*)&Bs[g & 1][(brow + n * 16) * 32 + kc * 8];
            if (g + 1 < G) STAGE_B(g + 1);           // writes other buffer: no alias with reads
            #pragma unroll
            for (int m = 0; m < 4; ++m)
                #pragma unroll
                for (int n = 0; n < 4; ++n)
                    acc[m][n] = __builtin_amdgcn_mfma_f32_16x16x32_bf16(af[m][kt], bfr[n], acc[m][n], 0, 0, 0);
        }

        // ---- epilogue for tile (ti, tj) ----
        float cs[4] = {0.f, 0.f, 0.f, 0.f};
        #pragma unroll
        for (int m = 0; m < 4; ++m) {
            f32x4 ef[4];
            #pragma unroll
            for (int n = 0; n < 4; ++n) ef[n] = exp4(acc[m][n]);
            #pragma unroll
            for (int n = 0; n < 4; ++n)
                acc[m][n] = (f32x4){0.f, 0.f, 0.f, 0.f};    // re-zero for next jt
            f32x4 rv = ef[0] + ef[1] + ef[2] + ef[3];
            #pragma unroll
            for (int msk = 1; msk <= 8; msk <<= 1) {
                rv.x += __shfl_xor(rv.x, msk, 64);
                rv.y += __shfl_xor(rv.y, msk, 64);
                rv.z += __shfl_xor(rv.z, msk, 64);
                rv.w += __shfl_xor(rv.w, msk, 64);
            }
            if ((lane & 15) == 0) {
                int rbase = wr * 64 + m * 16 + (lane >> 4) * 4;
                rPpart[wc][rbase + 0] = rv.x;
                rPpart[wc][rbase + 1] = rv.y;
                rPpart[wc][rbase + 2] = rv.z;
                rPpart[wc][rbase + 3] = rv.w;
            }
            #pragma unroll
            for (int n = 0; n < 4; ++n)
                cs[n] += ef[n].x + ef[n].y + ef[n].z + ef[n].w;
        }
        #pragma unroll
        for (int n = 0; n < 4; ++n) {
            float c = cs[n];
            c += __shfl_xor(c, 16, 64);
            c += __shfl_xor(c, 32, 64);
            if (lane < 16) cPpart[wr][wc * 64 + n * 16 + lane] = c;
        }
        __syncthreads();                             // partials visible

        if (tid < BT) {
            // row-sums of i-panel: slot tj, segment ti (unique writer per (ti,tj))
            P[(size_t)tj * N_ROWS + (size_t)ti * BT + tid] = rPpart[0][tid] + rPpart[1][tid];
        } else if (tj != ti) {
            int t = tid - BT;
            // col-sums -> rows of j-panel: slot ti, segment tj (ti<tj only)
            P[(size_t)ti * N_ROWS + (size_t)tj * BT + t] = cPpart[0][t] + cPpart[1][t];
        }
        // next jt's first __syncthreads orders rPpart/cPpart reuse
    }
#undef STAGE_B
}

// ------------- Kernel E: per-row reduce over 64 slots + log (+fold pos) -------------
__global__ __launch_bounds__(256) void reduce_rows_kernel(const float* __restrict__ P,
                                                          const float* __restrict__ pospartial,
                                                          float* __restrict__ blockpart) {
    const float E2 = 7.38905609893065f;   // exp(self-sim) = e^2
    int row = blockIdx.x * 256 + threadIdx.x;
    float s = 0.f;
    #pragma unroll 16
    for (int src = 0; src < TGRID; ++src)
        s += P[(size_t)src * N_ROWS + row];
    float v = logf(s - E2);
    if (threadIdx.x < 128)
        v -= 2.0f * pospartial[blockIdx.x * 128 + threadIdx.x];
    #pragma unroll
    for (int m = 1; m < 64; m <<= 1) v += __shfl_xor(v, m, 64);
    __shared__ float ws[4];
    if ((threadIdx.x & 63) == 0) ws[threadIdx.x >> 6] = v;
    __syncthreads();
    if (threadIdx.x == 0) blockpart[blockIdx.x] = ws[0] + ws[1] + ws[2] + ws[3];
}

// ------------- Kernel F: out = sum(blockpart) / N -------------
__global__ __launch_bounds__(64) void final_kernel(const float* __restrict__ blockpart,
                                                   float* __restrict__ out) {
    int lane = threadIdx.x;
    float v = (lane < 32) ? blockpart[lane] : 0.f;
    #pragma unroll
    for (int m = 1; m < 64; m <<= 1) v += __shfl_xor(v, m, 64);
    if (lane == 0) out[0] = v / (float)N_ROWS;
}

extern "C" void kernel_launch(void* const* d_in, const int* in_sizes, int n_in,
                              void* d_out, int out_size, void* d_ws, size_t ws_size,
                              hipStream_t stream) {
    const float* zi = (const float*)d_in[0];
    const float* zj = (const float*)d_in[1];
    char* ws = (char*)d_ws;
    unsigned short* zn = (unsigned short*)ws;                        // 4 MB
    float* P = (float*)(ws + 4 * 1024 * 1024);                       // 2 MB (64 x 8192 f32)
    float* pospartial = (float*)(ws + 6 * 1024 * 1024);              // 16 KB
    float* blockpart = (float*)(ws + 6 * 1024 * 1024 + 16 * 1024);   // 128 B

    normpos_kernel<<<B_ROWS / 4, 256, 0, stream>>>(zi, zj, zn, pospartial);
    simclr_gemm_kernel<<<NBLOCKS, 256, 0, stream>>>(zn, P);
    reduce_rows_kernel<<<N_ROWS / 256, 256, 0, stream>>>(P, pospartial, blockpart);
    final_kernel<<<1, 64, 0, stream>>>(blockpart, (float*)d_out);
}

// Round 11
// 38.195 us; speedup vs baseline: 1.8303x; 1.8303x over previous
//
#include <hip/hip_runtime.h>
#include <cstdint>

#define B_ROWS 4096
#define N_ROWS 8192
#define D_DIM  256
#define BT     128                 // block tile 128x128
#define TGRID  64                  // 8192 / 128
#define NTILES 2080                // TGRID*(TGRID+1)/2
#define NKT    4                   // 256 / 64 K-steps (BK=64, fp8)

typedef __attribute__((ext_vector_type(4))) float f32x4;
typedef __attribute__((ext_vector_type(2))) unsigned long u64x2;

__device__ __forceinline__ void gload16(const void* g, void* l) {
    __builtin_amdgcn_global_load_lds(
        (const __attribute__((address_space(1))) void*)g,
        (__attribute__((address_space(3))) void*)l, 16, 0, 0);
}

__device__ __forceinline__ f32x4 exp4(f32x4 v) {
    f32x4 r;
    r.x = __expf(v.x); r.y = __expf(v.y); r.z = __expf(v.z); r.w = __expf(v.w);
    return r;
}

// f32 -> fp8 e4m3fn (OCP), RNE, with subnormal support. |f| < 448 assumed.
__device__ __forceinline__ unsigned f2e4m3(float f) {
    union { float f; unsigned u; } v; v.f = f;
    unsigned s = (v.u >> 24) & 0x80u;
    unsigned mag = v.u & 0x7fffffffu;
    int e = (int)(mag >> 23) - 127;
    if (e >= -6) {  // normal range for e4m3
        unsigned r = mag + 0x7ffffu + ((mag >> 20) & 1u);   // RNE into 3 mantissa bits
        int e2 = (int)(r >> 23) - 127;
        unsigned m3 = (r >> 20) & 7u;
        return s | (unsigned)((e2 + 7) << 3) | m3;
    }
    if (e < -10) return s;                                   // underflow to 0
    float q = rintf(fabsf(f) * 512.0f);                      // subnormal: units of 2^-9
    unsigned qi = (unsigned)q;                               // 0..8
    return s | qi;                                           // qi==8 -> 0x08 == 2^-6 normal
}

// ------------- Kernel A: normalize pair rows -> fp8 zn (grouped layout) + pos dot -------------
// zn row layout (256 B): 4 K-groups of 64 B; group g, 16B unit y in [0,4):
//   bytes [g*64 + y*16 .. +8)  = k in [g*64 + y*8,      +8)   (K-half 0)
//   bytes [g*64 + y*16 + 8 ..) = k in [g*64 + 32 + y*8, +8)   (K-half 1)
// lane l covers k = l*4..l*4+4 -> one u32 at byte g*64 + c*16 + h*8 + 4*(l&1),
//   g = l>>4, c = (l>>1)&3, h = (l>>3)&1.
__global__ __launch_bounds__(256) void normpos_kernel(const float* __restrict__ zi,
                                                      const float* __restrict__ zj,
                                                      unsigned char* __restrict__ zn,
                                                      float* __restrict__ pospartial) {
    int wid = threadIdx.x >> 6;
    int lane = threadIdx.x & 63;
    int p = blockIdx.x * 4 + wid;          // 0..B_ROWS-1
    f32x4 ga = *(const f32x4*)(zi + (size_t)p * D_DIM + lane * 4);
    f32x4 gb = *(const f32x4*)(zj + (size_t)p * D_DIM + lane * 4);
    float sa = ga.x * ga.x + ga.y * ga.y + ga.z * ga.z + ga.w * ga.w;
    float sb = gb.x * gb.x + gb.y * gb.y + gb.z * gb.z + gb.w * gb.w;
    #pragma unroll
    for (int m = 1; m < 64; m <<= 1) { sa += __shfl_xor(sa, m, 64); sb += __shfl_xor(sb, m, 64); }
    float fa = 1.41421356237309515f / fmaxf(sqrtf(sa), 1e-8f);
    float fb = 1.41421356237309515f / fmaxf(sqrtf(sb), 1e-8f);
    f32x4 na, nb;
    na.x = ga.x * fa; na.y = ga.y * fa; na.z = ga.z * fa; na.w = ga.w * fa;
    nb.x = gb.x * fb; nb.y = gb.y * fb; nb.z = gb.z * fb; nb.w = gb.w * fb;
    unsigned pa = f2e4m3(na.x) | (f2e4m3(na.y) << 8) | (f2e4m3(na.z) << 16) | (f2e4m3(na.w) << 24);
    unsigned pb = f2e4m3(nb.x) | (f2e4m3(nb.y) << 8) | (f2e4m3(nb.z) << 16) | (f2e4m3(nb.w) << 24);
    int bytepos = (lane >> 4) * 64 + ((lane >> 1) & 3) * 16 + ((lane >> 3) & 1) * 8 + 4 * (lane & 1);
    *(unsigned*)(zn + (size_t)p * 256 + bytepos) = pa;
    *(unsigned*)(zn + (size_t)(p + B_ROWS) * 256 + bytepos) = pb;
    // pos dot in f32 (reference-accurate)
    float d = na.x * nb.x + na.y * nb.y + na.z * nb.z + na.w * nb.w;
    #pragma unroll
    for (int m = 1; m < 64; m <<= 1) d += __shfl_xor(d, m, 64);
    if (lane == 0) pospartial[p] = d;
}

// ------------- Kernel C: fp8 upper-tri 128x128 GEMM + exp + partial row/col sums -------------
// R9 discipline: 4 waves (2x2), wave-tile 64x64 (acc 4x4), BK=64 (4 steps), single LDS
// buffer, plain __syncthreads. ds_read_b128 -> two K=32 fp8 MFMAs. Swizzle: 16B slot
// y stored at y ^ ((row>>1)&3); source pre-swizzled sch = (t&3) ^ ((t>>3)&3).
__global__ __launch_bounds__(256, 3) void simclr_gemm_kernel(const unsigned char* __restrict__ zn,
                                                             float* __restrict__ P) {
    __shared__ unsigned char As[BT * 64];   // 8 KB (128 rows x 64 B)
    __shared__ unsigned char Bs[BT * 64];   // 8 KB
    __shared__ float rPpart[2][BT];
    __shared__ float cPpart[2][BT];

    const int tid = threadIdx.x;
    const int lane = tid & 63, wid = tid >> 6;
    const int wr = wid >> 1, wc = wid & 1;      // 2x2 wave grid

    // XCD-bijective chunked swizzle (2080 % 8 == 0)
    int bid = (int)((blockIdx.x & 7) * (NTILES / 8) + (blockIdx.x >> 3));
    // decode bid -> (ti,tj), ti<=tj, row-major upper triangle (TGRID=64)
    int ti = (int)((129.0f - sqrtf(16641.0f - 8.0f * (float)bid)) * 0.5f);
    while ((ti + 1) * TGRID - ((ti + 1) * ti) / 2 <= bid) ++ti;
    while (ti * TGRID - (ti * (ti - 1)) / 2 > bid) --ti;
    const int tj = ti + (bid - (ti * TGRID - (ti * (ti - 1)) / 2));

    const char* gA = (const char*)zn + (size_t)ti * BT * 256;   // row stride 256 B
    const char* gB = (const char*)zn + (size_t)tj * BT * 256;

    // staging: per K-64 step each matrix = 128 rows x 64 B = 8 KB = 2 issues of 4 KB.
    // thread -> (row = tid>>2 [+64], slot = tid&3); LDS byte = tid*16 [+4096].
    // source 16B chunk pre-swizzled: sch = (tid&3) ^ ((tid>>3)&3) = slot ^ ((row>>1)&3).
    const int r0 = tid >> 2;
    const int sch = (tid & 3) ^ ((tid >> 3) & 3);
    const size_t gof0 = (size_t)r0 * 256 + (size_t)sch * 16;
    const size_t gof1 = (size_t)(64 + r0) * 256 + (size_t)sch * 16;
    const unsigned lo0 = (unsigned)tid * 16;
    const unsigned lo1 = 4096u + (unsigned)tid * 16;

    f32x4 acc[4][4];
    #pragma unroll
    for (int m = 0; m < 4; ++m)
        #pragma unroll
        for (int n = 0; n < 4; ++n)
            acc[m][n] = (f32x4){0.f, 0.f, 0.f, 0.f};

    // frag read: row r, 16B unit y=(lane>>4) at byte r*64 + (y ^ ((r>>1)&3))*16;
    // frag row bases are x16 so (r>>1)&3 = ((lane&15)>>1)&3.
    const int ysw = (lane >> 4) ^ (((lane & 15) >> 1) & 3);
    const int arow = wr * 64 + (lane & 15);
    const int brow = wc * 64 + (lane & 15);

    #pragma unroll
    for (int kt = 0; kt < NKT; ++kt) {
        const size_t kb = (size_t)kt * 64;
        gload16(gA + gof0 + kb, &As[lo0]);
        gload16(gA + gof1 + kb, &As[lo1]);
        gload16(gB + gof0 + kb, &Bs[lo0]);
        gload16(gB + gof1 + kb, &Bs[lo1]);
        __syncthreads();            // staged data visible

        u64x2 af[4], bfr[4];
        #pragma unroll
        for (int m = 0; m < 4; ++m)
            af[m] = *(const u64x2*)&As[(arow + m * 16) * 64 + ysw * 16];
        #pragma unroll
        for (int n = 0; n < 4; ++n)
            bfr[n] = *(const u64x2*)&Bs[(brow + n * 16) * 64 + ysw * 16];

        #pragma unroll
        for (int m = 0; m < 4; ++m)
            #pragma unroll
            for (int n = 0; n < 4; ++n) {
                acc[m][n] = __builtin_amdgcn_mfma_f32_16x16x32_fp8_fp8(
                    (long)af[m].x, (long)bfr[n].x, acc[m][n], 0, 0, 0);
                acc[m][n] = __builtin_amdgcn_mfma_f32_16x16x32_fp8_fp8(
                    (long)af[m].y, (long)bfr[n].y, acc[m][n], 0, 0, 0);
            }
        __syncthreads();            // reads done before next stage overwrites
    }

    // ---- epilogue: exp; unique-writer LDS partials (no atomics) ----
    float cs[4] = {0.f, 0.f, 0.f, 0.f};
    #pragma unroll
    for (int m = 0; m < 4; ++m) {
        f32x4 ef[4];
        #pragma unroll
        for (int n = 0; n < 4; ++n) ef[n] = exp4(acc[m][n]);
        f32x4 rv = ef[0] + ef[1] + ef[2] + ef[3];
        #pragma unroll
        for (int msk = 1; msk <= 8; msk <<= 1) {
            rv.x += __shfl_xor(rv.x, msk, 64);
            rv.y += __shfl_xor(rv.y, msk, 64);
            rv.z += __shfl_xor(rv.z, msk, 64);
            rv.w += __shfl_xor(rv.w, msk, 64);
        }
        if ((lane & 15) == 0) {
            int rbase = wr * 64 + m * 16 + (lane >> 4) * 4;
            rPpart[wc][rbase + 0] = rv.x;
            rPpart[wc][rbase + 1] = rv.y;
            rPpart[wc][rbase + 2] = rv.z;
            rPpart[wc][rbase + 3] = rv.w;
        }
        #pragma unroll
        for (int n = 0; n < 4; ++n)
            cs[n] += ef[n].x + ef[n].y + ef[n].z + ef[n].w;
    }
    #pragma unroll
    for (int n = 0; n < 4; ++n) {
        float c = cs[n];
        c += __shfl_xor(c, 16, 64);
        c += __shfl_xor(c, 32, 64);
        if (lane < 16) cPpart[wr][wc * 64 + n * 16 + lane] = c;
    }
    __syncthreads();

    if (tid < BT) {
        P[(size_t)tj * N_ROWS + ti * BT + tid] = rPpart[0][tid] + rPpart[1][tid];
    } else if (ti != tj) {
        int t = tid - BT;
        P[(size_t)ti * N_ROWS + tj * BT + t] = cPpart[0][t] + cPpart[1][t];
    }
}

// ------------- Kernel E: per-row reduce over 64 slots + log (+fold pos) -------------
__global__ __launch_bounds__(256) void reduce_rows_kernel(const float* __restrict__ P,
                                                          const float* __restrict__ pospartial,
                                                          float* __restrict__ blockpart) {
    const float E2 = 7.38905609893065f;   // exp(self-sim) = e^2
    int row = blockIdx.x * 256 + threadIdx.x;
    float s = 0.f;
    #pragma unroll 16
    for (int src = 0; src < TGRID; ++src)
        s += P[(size_t)src * N_ROWS + row];
    float v = logf(s - E2);
    if (threadIdx.x < 128)
        v -= 2.0f * pospartial[blockIdx.x * 128 + threadIdx.x];
    #pragma unroll
    for (int m = 1; m < 64; m <<= 1) v += __shfl_xor(v, m, 64);
    __shared__ float ws[4];
    if ((threadIdx.x & 63) == 0) ws[threadIdx.x >> 6] = v;
    __syncthreads();
    if (threadIdx.x == 0) blockpart[blockIdx.x] = ws[0] + ws[1] + ws[2] + ws[3];
}

// ------------- Kernel F: out = sum(blockpart) / N -------------
__global__ __launch_bounds__(64) void final_kernel(const float* __restrict__ blockpart,
                                                   float* __restrict__ out) {
    int lane = threadIdx.x;
    float v = (lane < 32) ? blockpart[lane] : 0.f;
    #pragma unroll
    for (int m = 1; m < 64; m <<= 1) v += __shfl_xor(v, m, 64);
    if (lane == 0) out[0] = v / (float)N_ROWS;
}

extern "C" void kernel_launch(void* const* d_in, const int* in_sizes, int n_in,
                              void* d_out, int out_size, void* d_ws, size_t ws_size,
                              hipStream_t stream) {
    const float* zi = (const float*)d_in[0];
    const float* zj = (const float*)d_in[1];
    char* ws = (char*)d_ws;
    unsigned char* zn = (unsigned char*)ws;                          // 2 MB (8192 x 256 B)
    float* P = (float*)(ws + 2 * 1024 * 1024);                       // 2 MB (64 x 8192 f32)
    float* pospartial = (float*)(ws + 4 * 1024 * 1024);              // 16 KB
    float* blockpart = (float*)(ws + 4 * 1024 * 1024 + 16 * 1024);   // 128 B

    normpos_kernel<<<B_ROWS / 4, 256, 0, stream>>>(zi, zj, zn, pospartial);
    simclr_gemm_kernel<<<NTILES, 256, 0, stream>>>(zn, P);
    reduce_rows_kernel<<<N_ROWS / 256, 256, 0, stream>>>(P, pospartial, blockpart);
    final_kernel<<<1, 64, 0, stream>>>(blockpart, (float*)d_out);
}